// Round 9
// baseline (95.227 us; speedup 1.0000x reference)
//
#include <hip/hip_runtime.h>
#include <hip/hip_bf16.h>

#define FEATN 501
#define KPAD 1024
#define MSTRIDE 1032   // Ml row stride (ushorts): 2064 B -> 2-way (free) b128 conflicts
#define NB 8192
#define NT 512
#define DTC 0.01f

typedef __attribute__((ext_vector_type(8))) short short8;
typedef __attribute__((ext_vector_type(4))) short short4v;
typedef __attribute__((ext_vector_type(4))) float f32x4;

__device__ __forceinline__ float softplus_f(float x) {
    return fmaxf(x, 0.f) + log1pf(expf(-fabsf(x)));
}
__device__ __forceinline__ ushort f2bf(float x) {
    __hip_bfloat16 h = __float2bfloat16(x);   // RNE
    return *reinterpret_cast<ushort*>(&h);
}
__device__ __forceinline__ void gl_lds16(const void* g, void* l) {
    __builtin_amdgcn_global_load_lds(
        (const __attribute__((address_space(1))) void*)g,
        (__attribute__((address_space(3))) void*)l, 16, 0, 0);
}
// one DPP-add reduction step (pure VALU, no DS)
__device__ __forceinline__ float dpp_add(float x, const int ctrl) {
    int s = __builtin_bit_cast(int, x);
    int y;
    switch (ctrl) {   // ctrl must be a literal constant per call site
    case 0xB1:  y = __builtin_amdgcn_update_dpp(0, s, 0xB1, 0xf, 0xf, true); break;
    case 0x4E:  y = __builtin_amdgcn_update_dpp(0, s, 0x4E, 0xf, 0xf, true); break;
    default:    y = __builtin_amdgcn_update_dpp(0, s, 0x141, 0xf, 0xf, true); break;
    }
    return x + __builtin_bit_cast(float, y);
}

// ---------------- wtrans: W[1002][64]x2 -> Wt[128][1024] bf16 --------------
// k-map: k' in [0,501) -> W row k' (E part); k' in [512,1013) -> W row k'-11
// (nu part); else 0. Matches enc's Ml layout (8B-aligned LDS writes).
__global__ __launch_bounds__(256) void wtrans_kernel(
    const float* __restrict__ Bw1, const float* __restrict__ bw1,
    ushort* __restrict__ Wt) {
    const int h = blockIdx.x;
    const int lane = threadIdx.x & 63;
    const int wv = threadIdx.x >> 6;
    const float* W = (h < 64) ? Bw1 : bw1;
    const int col = h & 63;
    #pragma unroll
    for (int it = 0; it < 4; ++it) {
        const int k = it * 256 + wv * 64 + lane;
        const int ksrc = (k < FEATN) ? k
                       : (k >= 512 && k < 512 + FEATN) ? k - 11 : -1;
        const float v = (ksrc >= 0) ? W[(size_t)ksrc * 64 + col] : 0.f;
        Wt[(size_t)h * KPAD + k] = f2bf(v);
    }
}

// ---------------- enc (fused prep + GEMM): coefs for 16 batches ------------
// grid 512 x 256. Phase A: read E/nu, harmonic stats, bf16 -> static Ml LDS.
// K-loop: W-frags as global b128 (L2-resident Wt), B-frags from Ml, NO
// barriers -> compiler pipelines loads across steps.
// NOTE: idempotent (output cb does not feed its own inputs) -> launched twice
// this round to measure its marginal duration from total dur_us.
__global__ __launch_bounds__(256) void enc_kernel(
    const float* __restrict__ E, const float* __restrict__ nu,
    const ushort* __restrict__ Wt,
    const float* __restrict__ Bb1, const float* __restrict__ bb1,
    const float* __restrict__ Bw2, const float* __restrict__ Bb2,
    const float* __restrict__ bw2, const float* __restrict__ bb2,
    float* __restrict__ xi) {
    __shared__ ushort Ml[16 * MSTRIDE];   // [b][k'] bf16, ~33 KB, static
    __shared__ float hid[128][17];
    __shared__ float nups[16], Eps[16];

    const int tid = threadIdx.x;
    const int wv = tid >> 6, lane = tid & 63;
    const int bb0 = blockIdx.x * 16;

    // ---- phase A: 16 threads per batch ----
    {
        const int bl = tid >> 4;          // 0..15
        const int t16 = tid & 15;
        const size_t base = (size_t)(bb0 + bl) * FEATN;
        float s1 = 0.f, s2 = 0.f;
        #pragma unroll
        for (int it = 0; it < 8; ++it) {
            const int i0 = it * 64 + t16 * 4;
            if (i0 + 3 < FEATN) {
                const float4 Ev = *(const float4*)(E + base + i0);
                const float4 nv = *(const float4*)(nu + base + i0);
                const float i0v = 1.0f / nv.x, i1v = 1.0f / nv.y;
                const float i2v = 1.0f / nv.z, i3v = 1.0f / nv.w;
                s1 += (i0v + i1v) + (i2v + i3v);
                s2 = fmaf(Ev.x, i0v * i0v, s2);
                s2 = fmaf(Ev.y, i1v * i1v, s2);
                s2 = fmaf(Ev.z, i2v * i2v, s2);
                s2 = fmaf(Ev.w, i3v * i3v, s2);
                short4v ep = {(short)f2bf(Ev.x), (short)f2bf(Ev.y),
                              (short)f2bf(Ev.z), (short)f2bf(Ev.w)};
                short4v np_ = {(short)f2bf(nv.x), (short)f2bf(nv.y),
                               (short)f2bf(nv.z), (short)f2bf(nv.w)};
                *(short4v*)&Ml[bl * MSTRIDE + i0] = ep;
                *(short4v*)&Ml[bl * MSTRIDE + 512 + i0] = np_;
            } else if (i0 < FEATN) {      // i0 == 500
                const float Ev = E[base + i0];
                const float nv = nu[base + i0];
                const float iv = 1.0f / nv;
                s1 += iv;
                s2 = fmaf(Ev, iv * iv, s2);
                Ml[bl * MSTRIDE + i0] = f2bf(Ev);
                Ml[bl * MSTRIDE + 512 + i0] = f2bf(nv);
            }
        }
        if (t16 < 11) {                   // zero pads 501..511, 1013..1023
            Ml[bl * MSTRIDE + FEATN + t16] = 0;
            Ml[bl * MSTRIDE + 512 + FEATN + t16] = 0;
        }
        #pragma unroll
        for (int o = 1; o < 16; o <<= 1) {
            s1 += __shfl_xor(s1, o);
            s2 += __shfl_xor(s2, o);
        }
        if (t16 == 0) {
            const float np = (float)FEATN / s1;
            nups[bl] = np;
            Eps[bl] = (s2 / (float)FEATN) * np * np;
        }
    }
    __syncthreads();

    // ---- K loop: no barriers, W from L2, B from static LDS ----
    const int r15 = lane & 15, kg = lane >> 4;
    const ushort* wp0 = Wt + (size_t)(wv * 32 + r15) * KPAD + kg * 8;
    const ushort* wp1 = wp0 + 16 * KPAD;
    const int boff = r15 * MSTRIDE + kg * 8;

    f32x4 acc0 = {0.f, 0.f, 0.f, 0.f}, acc1 = acc0;
    #pragma unroll 4
    for (int s = 0; s < 32; ++s) {
        const int kb = s * 32;
        const short8 a0 = *(const short8*)(wp0 + kb);
        const short8 a1 = *(const short8*)(wp1 + kb);
        const short8 b = *(const short8*)&Ml[boff + kb];
        acc0 = __builtin_amdgcn_mfma_f32_16x16x32_bf16(a0, b, acc0, 0, 0, 0);
        acc1 = __builtin_amdgcn_mfma_f32_16x16x32_bf16(a1, b, acc1, 0, 0, 0);
    }

    // ---- bias + activation -> hid ----
    #pragma unroll
    for (int t = 0; t < 2; ++t) {
        #pragma unroll
        for (int r = 0; r < 4; ++r) {
            const int h = wv * 32 + t * 16 + kg * 4 + r;
            const float bias = (h < 64) ? Bb1[h] : bb1[h - 64];
            float v = (t ? acc1[r] : acc0[r]) + bias;
            v = (h < 64) ? fmaxf(v, 0.f) : softplus_f(v);
            hid[h][r15] = v;
        }
    }
    __syncthreads();

    // ---- layer 2 + coefficient write ----
    if (tid < 128) {
        const int bl = tid >> 3, k = tid & 7;
        float dB = 0.f, db = 0.f;
        #pragma unroll 8
        for (int h = 0; h < 64; ++h) {
            dB = fmaf(hid[h][bl], Bw2[h * 8 + k], dB);
            db = fmaf(hid[64 + h][bl], bw2[h * 8 + k], db);
        }
        const float Bm = dB + Bb2[k];
        const float be = softplus_f(db + bb2[k]);
        float Bs = Bm;
        Bs += __shfl_xor(Bs, 1);
        Bs += __shfl_xor(Bs, 2);
        Bs += __shfl_xor(Bs, 4);
        float* cb = xi + (size_t)(bb0 + bl) * 4096;
        cb[k] = 1.f - DTC * be * (Bm + Bs);
        cb[8 + k] = DTC * be * Bm;
        cb[16 + k] = Bm;
        if (k == 0) { cb[24] = Bs * Eps[bl]; cb[25] = nups[bl]; }
    }
}

// ---------------- time loop: LDS inputs, dwordx4 output stores -------------
// grid 2048 x 256: one wave per batch. lane = j*8+k. (unchanged from R8)
__global__ __launch_bounds__(256) void time_kernel(
    const float* __restrict__ e, const float* __restrict__ ed,
    const float* coef, float* stress, float* xi_out) {
    __shared__ float els[4][512];
    __shared__ float pls[4][512];
    __shared__ float scr[4][256];
    const int wv = threadIdx.x >> 6;
    const int wid = (blockIdx.x << 2) + wv;
    const int lane = threadIdx.x & 63;
    const int j = lane >> 3, k = lane & 7;

    const float* eb = e + (size_t)wid * NT;
    const float* edb = ed + (size_t)wid * NT;
    // stage this wave's entire input (wave-local: no barrier needed)
    gl_lds16(eb + lane * 4, &els[wv][0]);
    gl_lds16(eb + 256 + lane * 4, &els[wv][256]);
    gl_lds16(edb + lane * 4, &pls[wv][0]);
    gl_lds16(edb + 256 + lane * 4, &pls[wv][256]);

    const float* cb = coef + (size_t)wid * 4096;
    const float a = cb[k];
    const float c = cb[8 + k];
    const float Bm = cb[16 + k];
    const float sE = cb[24];
    const float nup = cb[25];
    // coef loads + LDS staging must land before LDS reads / aliased stores
    asm volatile("s_waitcnt vmcnt(0)" ::: "memory");

    // per-lane window constants: xi(t0+j) = a^j xi(t0) + sum_{i<j} a^(j-1-i) c u_i
    const float a2 = a * a, a4 = a2 * a2;
    float A = 1.f;                           // a^j
    if (j & 1) A *= a;
    if (j & 2) A *= a2;
    if (j & 4) A *= a4;
    float pw[8];                             // pw[i] = (i<j) ? a^(j-1-i)*c : 0
    {
        float run = c;
        #pragma unroll
        for (int i = 7; i >= 0; --i) {
            const bool on = (i < j);
            pw[i] = on ? run : 0.f;
            run = on ? run * a : run;
        }
    }

    float* xb = xi_out + (size_t)wid * (NT * 8);
    float* sb = stress + (size_t)wid * NT;
    const float* el = &els[wv][0];
    const float* pl = &pls[wv][0];

    // register-pipelined window reads from LDS
    float4 q0 = *(const float4*)(el);
    float4 q1 = *(const float4*)(el + 4);
    float uj = el[j];
    float pj = pl[j];

    float xs = 0.f;
    for (int g = 0; g < 16; ++g) {           // 4 windows = 32 timesteps/group
        const int T0 = g * 32;
        float vx[4], sv[4];
        #pragma unroll
        for (int w = 0; w < 4; ++w) {
            const int t0 = T0 + w * 8;
            const float u0 = q0.x, u1 = q0.y, u2 = q0.z, u3 = q0.w;
            const float u4 = q1.x, u5 = q1.y, u6 = q1.z, u7 = q1.w;
            const float cuj = uj, cpj = pj;
            if (t0 + 8 < NT) {               // prefetch next window (LDS)
                q0 = *(const float4*)(el + t0 + 8);
                q1 = *(const float4*)(el + t0 + 12);
                uj = el[t0 + 8 + j];
                pj = pl[t0 + 8 + j];
            }
            float xi_j = A * xs;
            xi_j = fmaf(pw[0], u0, xi_j);
            xi_j = fmaf(pw[1], u1, xi_j);
            xi_j = fmaf(pw[2], u2, xi_j);
            xi_j = fmaf(pw[3], u3, xi_j);
            xi_j = fmaf(pw[4], u4, xi_j);
            xi_j = fmaf(pw[5], u5, xi_j);
            xi_j = fmaf(pw[6], u6, xi_j);
            xi_j = fmaf(pw[7], u7, xi_j);
            vx[w] = xi_j;
            float r = Bm * (cuj - xi_j);
            r = dpp_add(r, 0xB1);            // + lane^1
            r = dpp_add(r, 0x4E);            // + lane^2
            r = dpp_add(r, 0x141);           // + other quad (within 8)
            sv[w] = fmaf(sE, cuj, fmaf(nup, cpj, r));
            // carry: x(t0+8) = a * x(t0+7) + c*u7 ; x(t0+7) sits in lane 56+k
            xs = fmaf(a, __shfl(xi_j, 56 + k), c * u7);
        }
        // xi repack: scratch idx = w*64 + lane == (t-T0)*8 + k
        #pragma unroll
        for (int w = 0; w < 4; ++w) scr[wv][w * 64 + lane] = vx[w];
        *(float4*)(xb + T0 * 8 + lane * 4) =
            *(const float4*)&scr[wv][lane * 4];          // 1KB/wave store
        // stress repack (reuse scr; per-wave LDS ops are in-order)
        if (k == 0) {
            #pragma unroll
            for (int w = 0; w < 4; ++w) scr[wv][w * 8 + j] = sv[w];
        }
        if (lane < 8)
            *(float4*)(sb + T0 + lane * 4) =
                *(const float4*)&scr[wv][lane * 4];      // 128B/wave store
    }
}

extern "C" void kernel_launch(void* const* d_in, const int* in_sizes, int n_in,
                              void* d_out, int out_size, void* d_ws, size_t ws_size,
                              hipStream_t stream) {
    const float* e   = (const float*)d_in[0];
    const float* ed  = (const float*)d_in[1];
    const float* E   = (const float*)d_in[2];
    const float* nu  = (const float*)d_in[3];
    const float* Bw1 = (const float*)d_in[4];
    const float* Bb1 = (const float*)d_in[5];
    const float* Bw2 = (const float*)d_in[6];
    const float* Bb2 = (const float*)d_in[7];
    const float* bw1 = (const float*)d_in[8];
    const float* bb1 = (const float*)d_in[9];
    const float* bw2 = (const float*)d_in[10];
    const float* bb2 = (const float*)d_in[11];

    float* out = (float*)d_out;
    float* stress = out;                        // [B*T] floats
    float* xi = out + (size_t)NB * NT;          // [B*T*8] floats
    ushort* Wt = (ushort*)out;                  // 256 KB stash in stress region

    wtrans_kernel<<<128, 256, 0, stream>>>(Bw1, bw1, Wt);
    // INSTRUMENTATION: enc launched twice (idempotent). Marginal dur_us vs
    // R8's 69.4 = enc's true steady-state duration.
    enc_kernel<<<512, 256, 0, stream>>>(E, nu, Wt, Bb1, bb1,
                                        Bw2, Bb2, bw2, bb2, xi);
    enc_kernel<<<512, 256, 0, stream>>>(E, nu, Wt, Bb1, bb1,
                                        Bw2, Bb2, bw2, bb2, xi);
    time_kernel<<<2048, 256, 0, stream>>>(e, ed, xi, stress, xi);
}

// Round 10
// 67.231 us; speedup vs baseline: 1.4164x; 1.4164x over previous
//
#include <hip/hip_runtime.h>
#include <hip/hip_bf16.h>

#define FEATN 501
#define KPAD 1024
#define MSTRIDE 1032   // Ml row stride (ushorts): 2064 B -> 2-way (free) b128 conflicts
#define NB 8192
#define NT 512
#define DTC 0.01f

typedef __attribute__((ext_vector_type(8))) short short8;
typedef __attribute__((ext_vector_type(4))) short short4v;
typedef __attribute__((ext_vector_type(4))) float f32x4;

__device__ __forceinline__ float softplus_f(float x) {
    return fmaxf(x, 0.f) + log1pf(expf(-fabsf(x)));
}
__device__ __forceinline__ ushort f2bf(float x) {
    __hip_bfloat16 h = __float2bfloat16(x);   // RNE
    return *reinterpret_cast<ushort*>(&h);
}
__device__ __forceinline__ void gl_lds16(const void* g, void* l) {
    __builtin_amdgcn_global_load_lds(
        (const __attribute__((address_space(1))) void*)g,
        (__attribute__((address_space(3))) void*)l, 16, 0, 0);
}
// one DPP-add reduction step (pure VALU, no DS)
__device__ __forceinline__ float dpp_add(float x, const int ctrl) {
    int s = __builtin_bit_cast(int, x);
    int y;
    switch (ctrl) {   // ctrl must be a literal constant per call site
    case 0xB1:  y = __builtin_amdgcn_update_dpp(0, s, 0xB1, 0xf, 0xf, true); break;
    case 0x4E:  y = __builtin_amdgcn_update_dpp(0, s, 0x4E, 0xf, 0xf, true); break;
    default:    y = __builtin_amdgcn_update_dpp(0, s, 0x141, 0xf, 0xf, true); break;
    }
    return x + __builtin_bit_cast(float, y);
}

// ---------------- wtrans: W[1002][64]x2 -> Wt[128][1024] bf16 --------------
// k-map: k' in [0,501) -> W row k' (E part); k' in [512,1013) -> W row k'-11
// (nu part); else 0. Matches enc's Ml layout (8B-aligned LDS writes).
__global__ __launch_bounds__(256) void wtrans_kernel(
    const float* __restrict__ Bw1, const float* __restrict__ bw1,
    ushort* __restrict__ Wt) {
    const int h = blockIdx.x;
    const int lane = threadIdx.x & 63;
    const int wv = threadIdx.x >> 6;
    const float* W = (h < 64) ? Bw1 : bw1;
    const int col = h & 63;
    #pragma unroll
    for (int it = 0; it < 4; ++it) {
        const int k = it * 256 + wv * 64 + lane;
        const int ksrc = (k < FEATN) ? k
                       : (k >= 512 && k < 512 + FEATN) ? k - 11 : -1;
        const float v = (ksrc >= 0) ? W[(size_t)ksrc * 64 + col] : 0.f;
        Wt[(size_t)h * KPAD + k] = f2bf(v);
    }
}

// ---------------- enc (fused prep + GEMM), 16 waves / 8 per SIMD -----------
// grid 512 x 1024. Phase A: one wave per batch streams E/nu (1KB/wave
// bursts), stats + bf16 -> Ml. K-loop: wave (g=w&3, q=w>>2) computes h-group
// g over K-quarter q (8 MFMA steps); partials combined via LDS red buffer.
__global__ __launch_bounds__(1024, 8) void enc_kernel(
    const float* __restrict__ E, const float* __restrict__ nu,
    const ushort* __restrict__ Wt,
    const float* __restrict__ Bb1, const float* __restrict__ bb1,
    const float* __restrict__ Bw2, const float* __restrict__ Bb2,
    const float* __restrict__ bw2, const float* __restrict__ bb2,
    float* __restrict__ xi) {
    __shared__ ushort Ml[16 * MSTRIDE];   // [b][k'] bf16, ~33 KB
    __shared__ float red[3][2048];        // K-partial exchange, 24 KB
    __shared__ float hid[128][17];        // activated hidden [h][b]
    __shared__ float nups[16], Eps[16];

    const int tid = threadIdx.x;
    const int w = tid >> 6, lane = tid & 63;
    const int bb0 = blockIdx.x * 16;

    // ---- phase A: one wave per batch ----
    {
        const int bl = w;                 // 0..15
        const size_t base = (size_t)(bb0 + bl) * FEATN;
        float s1 = 0.f, s2 = 0.f;
        #pragma unroll
        for (int it = 0; it < 2; ++it) {
            const int i0 = it * 256 + lane * 4;
            if (i0 + 3 < FEATN) {
                const float4 Ev = *(const float4*)(E + base + i0);
                const float4 nv = *(const float4*)(nu + base + i0);
                const float i0v = 1.0f / nv.x, i1v = 1.0f / nv.y;
                const float i2v = 1.0f / nv.z, i3v = 1.0f / nv.w;
                s1 += (i0v + i1v) + (i2v + i3v);
                s2 = fmaf(Ev.x, i0v * i0v, s2);
                s2 = fmaf(Ev.y, i1v * i1v, s2);
                s2 = fmaf(Ev.z, i2v * i2v, s2);
                s2 = fmaf(Ev.w, i3v * i3v, s2);
                short4v ep = {(short)f2bf(Ev.x), (short)f2bf(Ev.y),
                              (short)f2bf(Ev.z), (short)f2bf(Ev.w)};
                short4v np_ = {(short)f2bf(nv.x), (short)f2bf(nv.y),
                               (short)f2bf(nv.z), (short)f2bf(nv.w)};
                *(short4v*)&Ml[bl * MSTRIDE + i0] = ep;
                *(short4v*)&Ml[bl * MSTRIDE + 512 + i0] = np_;
            } else if (i0 < FEATN) {      // i0 == 500 (lane 61, it 1)
                const float Ev = E[base + i0];
                const float nv = nu[base + i0];
                const float iv = 1.0f / nv;
                s1 += iv;
                s2 = fmaf(Ev, iv * iv, s2);
                Ml[bl * MSTRIDE + i0] = f2bf(Ev);
                Ml[bl * MSTRIDE + 512 + i0] = f2bf(nv);
            }
        }
        if (lane < 11) {                  // zero pads 501..511, 1013..1023
            Ml[bl * MSTRIDE + FEATN + lane] = 0;
            Ml[bl * MSTRIDE + 512 + FEATN + lane] = 0;
        }
        #pragma unroll
        for (int o = 32; o; o >>= 1) {
            s1 += __shfl_xor(s1, o);
            s2 += __shfl_xor(s2, o);
        }
        if (lane == 0) {
            const float np = (float)FEATN / s1;
            nups[bl] = np;
            Eps[bl] = (s2 / (float)FEATN) * np * np;
        }
    }
    __syncthreads();

    // ---- K loop: wave (g, q); 8 steps over K-quarter ----
    const int g = w & 3, q = w >> 2;
    const int r15 = lane & 15, kg = lane >> 4;
    const ushort* wp0 = Wt + (size_t)(g * 32 + r15) * KPAD + q * 256 + kg * 8;
    const ushort* wp1 = wp0 + 16 * KPAD;
    const int boff = r15 * MSTRIDE + q * 256 + kg * 8;

    f32x4 acc0 = {0.f, 0.f, 0.f, 0.f}, acc1 = acc0;
    #pragma unroll
    for (int s = 0; s < 8; ++s) {
        const int kb = s * 32;
        const short8 a0 = *(const short8*)(wp0 + kb);
        const short8 a1 = *(const short8*)(wp1 + kb);
        const short8 b = *(const short8*)&Ml[boff + kb];
        acc0 = __builtin_amdgcn_mfma_f32_16x16x32_bf16(a0, b, acc0, 0, 0, 0);
        acc1 = __builtin_amdgcn_mfma_f32_16x16x32_bf16(a1, b, acc1, 0, 0, 0);
    }

    // ---- combine K-partials ----
    if (q > 0) {
        *(f32x4*)&red[q - 1][(g * 64 + lane) * 8] = acc0;
        *(f32x4*)&red[q - 1][(g * 64 + lane) * 8 + 4] = acc1;
    }
    __syncthreads();
    if (q == 0) {
        #pragma unroll
        for (int p = 0; p < 3; ++p) {
            acc0 += *(const f32x4*)&red[p][(g * 64 + lane) * 8];
            acc1 += *(const f32x4*)&red[p][(g * 64 + lane) * 8 + 4];
        }
        // bias + activation -> hid
        #pragma unroll
        for (int t = 0; t < 2; ++t) {
            #pragma unroll
            for (int r = 0; r < 4; ++r) {
                const int h = g * 32 + t * 16 + kg * 4 + r;
                const float bias = (h < 64) ? Bb1[h] : bb1[h - 64];
                float v = (t ? acc1[r] : acc0[r]) + bias;
                v = (h < 64) ? fmaxf(v, 0.f) : softplus_f(v);
                hid[h][r15] = v;
            }
        }
    }
    __syncthreads();

    // ---- layer 2 + coefficient write ----
    if (tid < 128) {
        const int bl = tid >> 3, k = tid & 7;
        float dB = 0.f, db = 0.f;
        #pragma unroll 8
        for (int h = 0; h < 64; ++h) {
            dB = fmaf(hid[h][bl], Bw2[h * 8 + k], dB);
            db = fmaf(hid[64 + h][bl], bw2[h * 8 + k], db);
        }
        const float Bm = dB + Bb2[k];
        const float be = softplus_f(db + bb2[k]);
        float Bs = Bm;
        Bs += __shfl_xor(Bs, 1);
        Bs += __shfl_xor(Bs, 2);
        Bs += __shfl_xor(Bs, 4);
        float* cb = xi + (size_t)(bb0 + bl) * 4096;
        cb[k] = 1.f - DTC * be * (Bm + Bs);
        cb[8 + k] = DTC * be * Bm;
        cb[16 + k] = Bm;
        if (k == 0) { cb[24] = Bs * Eps[bl]; cb[25] = nups[bl]; }
    }
}

// ---------------- time loop: LDS inputs, dwordx4 output stores -------------
// grid 2048 x 256: one wave per batch. lane = j*8+k. (unchanged from R8)
__global__ __launch_bounds__(256) void time_kernel(
    const float* __restrict__ e, const float* __restrict__ ed,
    const float* coef, float* stress, float* xi_out) {
    __shared__ float els[4][512];
    __shared__ float pls[4][512];
    __shared__ float scr[4][256];
    const int wv = threadIdx.x >> 6;
    const int wid = (blockIdx.x << 2) + wv;
    const int lane = threadIdx.x & 63;
    const int j = lane >> 3, k = lane & 7;

    const float* eb = e + (size_t)wid * NT;
    const float* edb = ed + (size_t)wid * NT;
    // stage this wave's entire input (wave-local: no barrier needed)
    gl_lds16(eb + lane * 4, &els[wv][0]);
    gl_lds16(eb + 256 + lane * 4, &els[wv][256]);
    gl_lds16(edb + lane * 4, &pls[wv][0]);
    gl_lds16(edb + 256 + lane * 4, &pls[wv][256]);

    const float* cb = coef + (size_t)wid * 4096;
    const float a = cb[k];
    const float c = cb[8 + k];
    const float Bm = cb[16 + k];
    const float sE = cb[24];
    const float nup = cb[25];
    // coef loads + LDS staging must land before LDS reads / aliased stores
    asm volatile("s_waitcnt vmcnt(0)" ::: "memory");

    // per-lane window constants: xi(t0+j) = a^j xi(t0) + sum_{i<j} a^(j-1-i) c u_i
    const float a2 = a * a, a4 = a2 * a2;
    float A = 1.f;                           // a^j
    if (j & 1) A *= a;
    if (j & 2) A *= a2;
    if (j & 4) A *= a4;
    float pw[8];                             // pw[i] = (i<j) ? a^(j-1-i)*c : 0
    {
        float run = c;
        #pragma unroll
        for (int i = 7; i >= 0; --i) {
            const bool on = (i < j);
            pw[i] = on ? run : 0.f;
            run = on ? run * a : run;
        }
    }

    float* xb = xi_out + (size_t)wid * (NT * 8);
    float* sb = stress + (size_t)wid * NT;
    const float* el = &els[wv][0];
    const float* pl = &pls[wv][0];

    // register-pipelined window reads from LDS
    float4 q0 = *(const float4*)(el);
    float4 q1 = *(const float4*)(el + 4);
    float uj = el[j];
    float pj = pl[j];

    float xs = 0.f;
    for (int g = 0; g < 16; ++g) {           // 4 windows = 32 timesteps/group
        const int T0 = g * 32;
        float vx[4], sv[4];
        #pragma unroll
        for (int w = 0; w < 4; ++w) {
            const int t0 = T0 + w * 8;
            const float u0 = q0.x, u1 = q0.y, u2 = q0.z, u3 = q0.w;
            const float u4 = q1.x, u5 = q1.y, u6 = q1.z, u7 = q1.w;
            const float cuj = uj, cpj = pj;
            if (t0 + 8 < NT) {               // prefetch next window (LDS)
                q0 = *(const float4*)(el + t0 + 8);
                q1 = *(const float4*)(el + t0 + 12);
                uj = el[t0 + 8 + j];
                pj = pl[t0 + 8 + j];
            }
            float xi_j = A * xs;
            xi_j = fmaf(pw[0], u0, xi_j);
            xi_j = fmaf(pw[1], u1, xi_j);
            xi_j = fmaf(pw[2], u2, xi_j);
            xi_j = fmaf(pw[3], u3, xi_j);
            xi_j = fmaf(pw[4], u4, xi_j);
            xi_j = fmaf(pw[5], u5, xi_j);
            xi_j = fmaf(pw[6], u6, xi_j);
            xi_j = fmaf(pw[7], u7, xi_j);
            vx[w] = xi_j;
            float r = Bm * (cuj - xi_j);
            r = dpp_add(r, 0xB1);            // + lane^1
            r = dpp_add(r, 0x4E);            // + lane^2
            r = dpp_add(r, 0x141);           // + other quad (within 8)
            sv[w] = fmaf(sE, cuj, fmaf(nup, cpj, r));
            // carry: x(t0+8) = a * x(t0+7) + c*u7 ; x(t0+7) sits in lane 56+k
            xs = fmaf(a, __shfl(xi_j, 56 + k), c * u7);
        }
        // xi repack: scratch idx = w*64 + lane == (t-T0)*8 + k
        #pragma unroll
        for (int w = 0; w < 4; ++w) scr[wv][w * 64 + lane] = vx[w];
        *(float4*)(xb + T0 * 8 + lane * 4) =
            *(const float4*)&scr[wv][lane * 4];          // 1KB/wave store
        // stress repack (reuse scr; per-wave LDS ops are in-order)
        if (k == 0) {
            #pragma unroll
            for (int w = 0; w < 4; ++w) scr[wv][w * 8 + j] = sv[w];
        }
        if (lane < 8)
            *(float4*)(sb + T0 + lane * 4) =
                *(const float4*)&scr[wv][lane * 4];      // 128B/wave store
    }
}

extern "C" void kernel_launch(void* const* d_in, const int* in_sizes, int n_in,
                              void* d_out, int out_size, void* d_ws, size_t ws_size,
                              hipStream_t stream) {
    const float* e   = (const float*)d_in[0];
    const float* ed  = (const float*)d_in[1];
    const float* E   = (const float*)d_in[2];
    const float* nu  = (const float*)d_in[3];
    const float* Bw1 = (const float*)d_in[4];
    const float* Bb1 = (const float*)d_in[5];
    const float* Bw2 = (const float*)d_in[6];
    const float* Bb2 = (const float*)d_in[7];
    const float* bw1 = (const float*)d_in[8];
    const float* bb1 = (const float*)d_in[9];
    const float* bw2 = (const float*)d_in[10];
    const float* bb2 = (const float*)d_in[11];

    float* out = (float*)d_out;
    float* stress = out;                        // [B*T] floats
    float* xi = out + (size_t)NB * NT;          // [B*T*8] floats
    ushort* Wt = (ushort*)out;                  // 256 KB stash in stress region

    wtrans_kernel<<<128, 256, 0, stream>>>(Bw1, bw1, Wt);
    enc_kernel<<<512, 1024, 0, stream>>>(E, nu, Wt, Bb1, bb1,
                                         Bw2, Bb2, bw2, bb2, xi);
    time_kernel<<<2048, 256, 0, stream>>>(e, ed, xi, stress, xi);
}

// Round 11
// 66.486 us; speedup vs baseline: 1.4323x; 1.0112x over previous
//
#include <hip/hip_runtime.h>
#include <hip/hip_bf16.h>

#define FEATN 501
#define KPAD 1024
#define MSTRIDE 1032   // Ml row stride (ushorts)
#define NB 8192
#define NT 512
#define DTC 0.01f

typedef __attribute__((ext_vector_type(8))) short short8;
typedef __attribute__((ext_vector_type(4))) short short4v;
typedef __attribute__((ext_vector_type(4))) float f32x4;

__device__ __forceinline__ float softplus_f(float x) {
    return fmaxf(x, 0.f) + log1pf(expf(-fabsf(x)));
}
__device__ __forceinline__ ushort f2bf(float x) {
    __hip_bfloat16 h = __float2bfloat16(x);   // RNE
    return *reinterpret_cast<ushort*>(&h);
}
__device__ __forceinline__ void gl_lds16(const void* g, void* l) {
    __builtin_amdgcn_global_load_lds(
        (const __attribute__((address_space(1))) void*)g,
        (__attribute__((address_space(3))) void*)l, 16, 0, 0);
}
__device__ __forceinline__ float dpp_add(float x, const int ctrl) {
    int s = __builtin_bit_cast(int, x);
    int y;
    switch (ctrl) {
    case 0xB1:  y = __builtin_amdgcn_update_dpp(0, s, 0xB1, 0xf, 0xf, true); break;
    case 0x4E:  y = __builtin_amdgcn_update_dpp(0, s, 0x4E, 0xf, 0xf, true); break;
    default:    y = __builtin_amdgcn_update_dpp(0, s, 0x141, 0xf, 0xf, true); break;
    }
    return x + __builtin_bit_cast(float, y);
}

// ---------------- wtrans: W[1002][64]x2 -> Wt[128][1024] bf16 (in d_ws) ----
__global__ __launch_bounds__(256) void wtrans_kernel(
    const float* __restrict__ Bw1, const float* __restrict__ bw1,
    ushort* __restrict__ Wt) {
    const int h = blockIdx.x;
    const int lane = threadIdx.x & 63;
    const int wv = threadIdx.x >> 6;
    const float* W = (h < 64) ? Bw1 : bw1;
    const int col = h & 63;
    #pragma unroll
    for (int it = 0; it < 4; ++it) {
        const int k = it * 256 + wv * 64 + lane;
        const int ksrc = (k < FEATN) ? k
                       : (k >= 512 && k < 512 + FEATN) ? k - 11 : -1;
        const float v = (ksrc >= 0) ? W[(size_t)ksrc * 64 + col] : 0.f;
        Wt[(size_t)h * KPAD + k] = f2bf(v);
    }
}

// ---------------- fused: enc (16 batches) + time loop, one block -----------
// 1024 threads = 16 waves; grid 512 = 2 blocks/CU (LDS ~68.5 KB). Phases:
// A: wave w streams E/nu of batch w -> stats + Ml. B: K-loop 4-way split ->
// red combine -> hid -> layer2 -> coefL (LDS only). C: wave w stages e/ed
// via global_load_lds into els/pls (aliases dead Ml/red/hid), runs the
// closed-form time loop. Cross-block phase overlap hides enc latency.
__global__ __launch_bounds__(1024, 8) void fused_kernel(
    const float* __restrict__ E, const float* __restrict__ nu,
    const ushort* __restrict__ Wt,
    const float* __restrict__ Bb1, const float* __restrict__ bb1,
    const float* __restrict__ Bw2, const float* __restrict__ Bb2,
    const float* __restrict__ bw2, const float* __restrict__ bb2,
    const float* __restrict__ e, const float* __restrict__ ed,
    float* __restrict__ stress, float* __restrict__ xi_out) {
    // union region: [Ml 33024B][red 24576B][hid 8704B] = 66304B  (phases A/B)
    //               [els 32768B][pls 32768B]           = 65536B  (phase C)
    __shared__ __align__(16) char LDSU[66304];
    ushort* Ml = (ushort*)LDSU;                                   // [16][MSTRIDE]
    float (*red)[2048] = (float(*)[2048])(LDSU + 33024);          // [3][2048]
    float (*hid)[17] = (float(*)[17])(LDSU + 57600);              // [128][17]
    float* els = (float*)LDSU;                                    // [16][512]
    float* pls = (float*)(LDSU + 32768);                          // [16][512]
    __shared__ float coefL[16][32];
    __shared__ float nups[16], Eps[16];

    const int tid = threadIdx.x;
    const int w = tid >> 6, lane = tid & 63;
    const int bb0 = blockIdx.x * 16;

    // ---- phase A: one wave per batch ----
    {
        const size_t base = (size_t)(bb0 + w) * FEATN;
        float s1 = 0.f, s2 = 0.f;
        #pragma unroll
        for (int it = 0; it < 2; ++it) {
            const int i0 = it * 256 + lane * 4;
            if (i0 + 3 < FEATN) {
                const float4 Ev = *(const float4*)(E + base + i0);
                const float4 nv = *(const float4*)(nu + base + i0);
                const float i0v = 1.0f / nv.x, i1v = 1.0f / nv.y;
                const float i2v = 1.0f / nv.z, i3v = 1.0f / nv.w;
                s1 += (i0v + i1v) + (i2v + i3v);
                s2 = fmaf(Ev.x, i0v * i0v, s2);
                s2 = fmaf(Ev.y, i1v * i1v, s2);
                s2 = fmaf(Ev.z, i2v * i2v, s2);
                s2 = fmaf(Ev.w, i3v * i3v, s2);
                short4v ep = {(short)f2bf(Ev.x), (short)f2bf(Ev.y),
                              (short)f2bf(Ev.z), (short)f2bf(Ev.w)};
                short4v np_ = {(short)f2bf(nv.x), (short)f2bf(nv.y),
                               (short)f2bf(nv.z), (short)f2bf(nv.w)};
                *(short4v*)&Ml[w * MSTRIDE + i0] = ep;
                *(short4v*)&Ml[w * MSTRIDE + 512 + i0] = np_;
            } else if (i0 < FEATN) {      // i0 == 500
                const float Ev = E[base + i0];
                const float nv = nu[base + i0];
                const float iv = 1.0f / nv;
                s1 += iv;
                s2 = fmaf(Ev, iv * iv, s2);
                Ml[w * MSTRIDE + i0] = f2bf(Ev);
                Ml[w * MSTRIDE + 512 + i0] = f2bf(nv);
            }
        }
        if (lane < 11) {                  // zero pads
            Ml[w * MSTRIDE + FEATN + lane] = 0;
            Ml[w * MSTRIDE + 512 + FEATN + lane] = 0;
        }
        #pragma unroll
        for (int o = 32; o; o >>= 1) {
            s1 += __shfl_xor(s1, o);
            s2 += __shfl_xor(s2, o);
        }
        if (lane == 0) {
            const float np = (float)FEATN / s1;
            nups[w] = np;
            Eps[w] = (s2 / (float)FEATN) * np * np;
        }
    }
    __syncthreads();

    // ---- phase B: K-loop, wave (g=w&3, q=w>>2), 8 steps over K-quarter ----
    const int g = w & 3, q = w >> 2;
    const int r15 = lane & 15, kg = lane >> 4;
    {
        const ushort* wp0 = Wt + (size_t)(g * 32 + r15) * KPAD + q * 256 + kg * 8;
        const ushort* wp1 = wp0 + 16 * KPAD;
        const int boff = r15 * MSTRIDE + q * 256 + kg * 8;

        f32x4 acc0 = {0.f, 0.f, 0.f, 0.f}, acc1 = acc0;
        #pragma unroll
        for (int s = 0; s < 8; ++s) {
            const int kb = s * 32;
            const short8 a0 = *(const short8*)(wp0 + kb);
            const short8 a1 = *(const short8*)(wp1 + kb);
            const short8 b = *(const short8*)&Ml[boff + kb];
            acc0 = __builtin_amdgcn_mfma_f32_16x16x32_bf16(a0, b, acc0, 0, 0, 0);
            acc1 = __builtin_amdgcn_mfma_f32_16x16x32_bf16(a1, b, acc1, 0, 0, 0);
        }
        if (q > 0) {
            *(f32x4*)&red[q - 1][(g * 64 + lane) * 8] = acc0;
            *(f32x4*)&red[q - 1][(g * 64 + lane) * 8 + 4] = acc1;
        }
        __syncthreads();
        if (q == 0) {
            #pragma unroll
            for (int p = 0; p < 3; ++p) {
                acc0 += *(const f32x4*)&red[p][(g * 64 + lane) * 8];
                acc1 += *(const f32x4*)&red[p][(g * 64 + lane) * 8 + 4];
            }
            #pragma unroll
            for (int t = 0; t < 2; ++t) {
                #pragma unroll
                for (int r = 0; r < 4; ++r) {
                    const int h = g * 32 + t * 16 + kg * 4 + r;
                    const float bias = (h < 64) ? Bb1[h] : bb1[h - 64];
                    float v = (t ? acc1[r] : acc0[r]) + bias;
                    v = (h < 64) ? fmaxf(v, 0.f) : softplus_f(v);
                    hid[h][r15] = v;
                }
            }
        }
    }
    __syncthreads();

    // ---- layer 2 -> coefL (LDS only; no global round-trip) ----
    if (tid < 128) {
        const int bl = tid >> 3, k = tid & 7;
        float dB = 0.f, db = 0.f;
        #pragma unroll 8
        for (int h = 0; h < 64; ++h) {
            dB = fmaf(hid[h][bl], Bw2[h * 8 + k], dB);
            db = fmaf(hid[64 + h][bl], bw2[h * 8 + k], db);
        }
        const float Bm = dB + Bb2[k];
        const float be = softplus_f(db + bb2[k]);
        float Bs = Bm;
        Bs += __shfl_xor(Bs, 1);
        Bs += __shfl_xor(Bs, 2);
        Bs += __shfl_xor(Bs, 4);
        coefL[bl][k] = 1.f - DTC * be * (Bm + Bs);
        coefL[bl][8 + k] = DTC * be * Bm;
        coefL[bl][16 + k] = Bm;
        if (k == 0) { coefL[bl][24] = Bs * Eps[bl]; coefL[bl][25] = nups[bl]; }
    }
    __syncthreads();   // Ml/red/hid dead; coefL ready; els/pls region free

    // ---- phase C: time loop (wave w = batch bb0+w) ----
    const int wid = bb0 + w;
    const int j = lane >> 3, k = lane & 7;
    const float* eb = e + (size_t)wid * NT;
    const float* edb = ed + (size_t)wid * NT;
    float* el = els + w * 512;
    float* pl = pls + w * 512;
    gl_lds16(eb + lane * 4, el);
    gl_lds16(eb + 256 + lane * 4, el + 256);
    gl_lds16(edb + lane * 4, pl);
    gl_lds16(edb + 256 + lane * 4, pl + 256);

    const float a = coefL[w][k];
    const float c = coefL[w][8 + k];
    const float Bm = coefL[w][16 + k];
    const float sE = coefL[w][24];
    const float nup = coefL[w][25];
    // staged e/ed must land before the LDS reads below
    asm volatile("s_waitcnt vmcnt(0)" ::: "memory");

    const float a2 = a * a, a4 = a2 * a2;
    float A = 1.f;                           // a^j
    if (j & 1) A *= a;
    if (j & 2) A *= a2;
    if (j & 4) A *= a4;
    float pw[8];                             // pw[i] = (i<j) ? a^(j-1-i)*c : 0
    {
        float run = c;
        #pragma unroll
        for (int i = 7; i >= 0; --i) {
            const bool on = (i < j);
            pw[i] = on ? run : 0.f;
            run = on ? run * a : run;
        }
    }

    float* xb = xi_out + (size_t)wid * (NT * 8);
    float* sb = stress + (size_t)wid * NT;

    float4 q0 = *(const float4*)(el);
    float4 q1 = *(const float4*)(el + 4);
    float uj = el[j];
    float pj = pl[j];

    float xs = 0.f;
    #pragma unroll 2
    for (int t0 = 0; t0 < NT; t0 += 8) {
        const float u0 = q0.x, u1 = q0.y, u2 = q0.z, u3 = q0.w;
        const float u4 = q1.x, u5 = q1.y, u6 = q1.z, u7 = q1.w;
        const float cuj = uj, cpj = pj;
        if (t0 + 8 < NT) {                   // prefetch next window (LDS)
            q0 = *(const float4*)(el + t0 + 8);
            q1 = *(const float4*)(el + t0 + 12);
            uj = el[t0 + 8 + j];
            pj = pl[t0 + 8 + j];
        }
        float xi_j = A * xs;
        xi_j = fmaf(pw[0], u0, xi_j);
        xi_j = fmaf(pw[1], u1, xi_j);
        xi_j = fmaf(pw[2], u2, xi_j);
        xi_j = fmaf(pw[3], u3, xi_j);
        xi_j = fmaf(pw[4], u4, xi_j);
        xi_j = fmaf(pw[5], u5, xi_j);
        xi_j = fmaf(pw[6], u6, xi_j);
        xi_j = fmaf(pw[7], u7, xi_j);
        xb[t0 * 8 + lane] = xi_j;            // coalesced 256B/wave
        float r = Bm * (cuj - xi_j);
        r = dpp_add(r, 0xB1);                // + lane^1
        r = dpp_add(r, 0x4E);                // + lane^2
        r = dpp_add(r, 0x141);               // + other quad (within 8)
        if (k == 0) sb[t0 + j] = fmaf(sE, cuj, fmaf(nup, cpj, r));
        // carry: x(t0+8) = a * x(t0+7) + c*u7 ; x(t0+7) sits in lane 56+k
        xs = fmaf(a, __shfl(xi_j, 56 + k), c * u7);
    }
}

extern "C" void kernel_launch(void* const* d_in, const int* in_sizes, int n_in,
                              void* d_out, int out_size, void* d_ws, size_t ws_size,
                              hipStream_t stream) {
    const float* e   = (const float*)d_in[0];
    const float* ed  = (const float*)d_in[1];
    const float* E   = (const float*)d_in[2];
    const float* nu  = (const float*)d_in[3];
    const float* Bw1 = (const float*)d_in[4];
    const float* Bb1 = (const float*)d_in[5];
    const float* Bw2 = (const float*)d_in[6];
    const float* Bb2 = (const float*)d_in[7];
    const float* bw1 = (const float*)d_in[8];
    const float* bb1 = (const float*)d_in[9];
    const float* bw2 = (const float*)d_in[10];
    const float* bb2 = (const float*)d_in[11];

    float* out = (float*)d_out;
    float* stress = out;                        // [B*T] floats
    float* xi = out + (size_t)NB * NT;          // [B*T*8] floats
    ushort* Wt = (ushort*)d_ws;                 // 256 KB scratch

    wtrans_kernel<<<128, 256, 0, stream>>>(Bw1, bw1, Wt);
    fused_kernel<<<512, 1024, 0, stream>>>(E, nu, Wt, Bb1, bb1,
                                           Bw2, Bb2, bw2, bb2,
                                           e, ed, stress, xi);
}

// Round 12
// 60.642 us; speedup vs baseline: 1.5703x; 1.0964x over previous
//
#include <hip/hip_runtime.h>
#include <hip/hip_bf16.h>

#define FEATN 501
#define KPAD 1024
#define MSTRIDE 1032   // Ml row stride (ushorts)
#define NB 8192
#define NT 512
#define DTC 0.01f

typedef __attribute__((ext_vector_type(8))) short short8;
typedef __attribute__((ext_vector_type(4))) float f32x4;

__device__ __forceinline__ float softplus_f(float x) {
    return fmaxf(x, 0.f) + log1pf(expf(-fabsf(x)));
}
__device__ __forceinline__ ushort f2bf(float x) {
    __hip_bfloat16 h = __float2bfloat16(x);   // RNE
    return *reinterpret_cast<ushort*>(&h);
}
__device__ __forceinline__ void gl_lds16(const void* g, void* l) {
    __builtin_amdgcn_global_load_lds(
        (const __attribute__((address_space(1))) void*)g,
        (__attribute__((address_space(3))) void*)l, 16, 0, 0);
}
__device__ __forceinline__ float dpp_add(float x, const int ctrl) {
    int s = __builtin_bit_cast(int, x);
    int y;
    switch (ctrl) {
    case 0xB1:  y = __builtin_amdgcn_update_dpp(0, s, 0xB1, 0xf, 0xf, true); break;
    case 0x4E:  y = __builtin_amdgcn_update_dpp(0, s, 0x4E, 0xf, 0xf, true); break;
    default:    y = __builtin_amdgcn_update_dpp(0, s, 0x141, 0xf, 0xf, true); break;
    }
    return x + __builtin_bit_cast(float, y);
}

// Wt2 tiled layout: idx(k,h) = ((s*128 + h)*4 + kg)*8 + kk
// with s = k>>5, kg = (k>>3)&3, kk = k&7. A wave's MFMA operand load
// (16 h-rows x 4 kg-slots x 16B) is then 1KB fully contiguous.
__global__ __launch_bounds__(256) void wtrans_kernel(
    const float* __restrict__ Bw1, const float* __restrict__ bw1,
    ushort* __restrict__ Wt) {
    const int h = blockIdx.x;
    const float* W = (h < 64) ? Bw1 : bw1;
    const int col = h & 63;
    #pragma unroll
    for (int it = 0; it < 4; ++it) {
        const int k = it * 256 + threadIdx.x;
        const int ksrc = (k < FEATN) ? k
                       : (k >= 512 && k < 512 + FEATN) ? k - 11 : -1;
        const float v = (ksrc >= 0) ? W[(size_t)ksrc * 64 + col] : 0.f;
        Wt[(size_t)(((k >> 5) * 128 + h) * 4 + ((k >> 3) & 3)) * 8 + (k & 7)] =
            f2bf(v);
    }
}

// ---------------- enc: 16 waves (8/SIMD), coalesced everywhere -------------
// grid 512 x 1024, 2 blocks/CU. Phase A: wave w = batch, stride-64 dword
// loads (aligned). Phase B: wave (g=w&3,q=w>>2), Wt2 tiled loads (1KB
// coalesced), 8 MFMA steps; red combine; layer2 -> coefs in d_ws.
__global__ __launch_bounds__(1024, 8) void enc_kernel(
    const float* __restrict__ E, const float* __restrict__ nu,
    const ushort* __restrict__ Wt,
    const float* __restrict__ Bb1, const float* __restrict__ bb1,
    const float* __restrict__ Bw2, const float* __restrict__ Bb2,
    const float* __restrict__ bw2, const float* __restrict__ bb2,
    float* __restrict__ cw) {
    __shared__ ushort Ml[16 * MSTRIDE];   // ~33 KB
    __shared__ float red[3][2048];        // 24 KB
    __shared__ float hid[128][17];        // 8.5 KB
    __shared__ float nups[16], Eps[16];

    const int tid = threadIdx.x;
    const int w = tid >> 6, lane = tid & 63;
    const int bb0 = blockIdx.x * 16;

    // ---- phase A: one wave per batch, stride-64 dword loads ----
    {
        const size_t base = (size_t)(bb0 + w) * FEATN;
        float s1 = 0.f, s2 = 0.f;
        for (int i = lane; i < FEATN; i += 64) {
            const float Ev = E[base + i];
            const float nv = nu[base + i];
            const float inv = 1.0f / nv;
            s1 += inv;
            s2 = fmaf(Ev, inv * inv, s2);
            Ml[w * MSTRIDE + i] = f2bf(Ev);
            Ml[w * MSTRIDE + 512 + i] = f2bf(nv);
        }
        if (lane < 11) {                  // zero pads 501..511, 1013..1023
            Ml[w * MSTRIDE + FEATN + lane] = 0;
            Ml[w * MSTRIDE + 512 + FEATN + lane] = 0;
        }
        #pragma unroll
        for (int o = 32; o; o >>= 1) {
            s1 += __shfl_xor(s1, o);
            s2 += __shfl_xor(s2, o);
        }
        if (lane == 0) {
            const float np = (float)FEATN / s1;
            nups[w] = np;
            Eps[w] = (s2 / (float)FEATN) * np * np;
        }
    }
    __syncthreads();

    // ---- phase B: wave (g,q), 8 MFMA steps over K-quarter ----
    const int g = w & 3, q = w >> 2;
    const int r15 = lane & 15, kg = lane >> 4;
    {
        // per step s' : block base advances 4096 ushorts (128 rows * 32)
        const ushort* wbase = Wt + (size_t)(q * 8) * 4096;
        const int aoff = (g * 32 + r15) * 32 + kg * 8;   // 16 rows x 4 slots = 1KB
        const int boff = r15 * MSTRIDE + q * 256 + kg * 8;

        f32x4 acc0 = {0.f, 0.f, 0.f, 0.f}, acc1 = acc0;
        #pragma unroll
        for (int s = 0; s < 8; ++s) {
            const short8 a0 = *(const short8*)(wbase + s * 4096 + aoff);
            const short8 a1 = *(const short8*)(wbase + s * 4096 + aoff + 512);
            const short8 b = *(const short8*)&Ml[boff + s * 32];
            acc0 = __builtin_amdgcn_mfma_f32_16x16x32_bf16(a0, b, acc0, 0, 0, 0);
            acc1 = __builtin_amdgcn_mfma_f32_16x16x32_bf16(a1, b, acc1, 0, 0, 0);
        }
        if (q > 0) {
            *(f32x4*)&red[q - 1][(g * 64 + lane) * 8] = acc0;
            *(f32x4*)&red[q - 1][(g * 64 + lane) * 8 + 4] = acc1;
        }
        __syncthreads();
        if (q == 0) {
            #pragma unroll
            for (int p = 0; p < 3; ++p) {
                acc0 += *(const f32x4*)&red[p][(g * 64 + lane) * 8];
                acc1 += *(const f32x4*)&red[p][(g * 64 + lane) * 8 + 4];
            }
            #pragma unroll
            for (int t = 0; t < 2; ++t) {
                #pragma unroll
                for (int r = 0; r < 4; ++r) {
                    const int h = g * 32 + t * 16 + kg * 4 + r;
                    const float bias = (h < 64) ? Bb1[h] : bb1[h - 64];
                    float v = (t ? acc1[r] : acc0[r]) + bias;
                    v = (h < 64) ? fmaxf(v, 0.f) : softplus_f(v);
                    hid[h][r15] = v;
                }
            }
        }
    }
    __syncthreads();

    // ---- layer 2 -> coef write (d_ws) ----
    if (tid < 128) {
        const int bl = tid >> 3, k = tid & 7;
        float dB = 0.f, db = 0.f;
        #pragma unroll 8
        for (int h = 0; h < 64; ++h) {
            dB = fmaf(hid[h][bl], Bw2[h * 8 + k], dB);
            db = fmaf(hid[64 + h][bl], bw2[h * 8 + k], db);
        }
        const float Bm = dB + Bb2[k];
        const float be = softplus_f(db + bb2[k]);
        float Bs = Bm;
        Bs += __shfl_xor(Bs, 1);
        Bs += __shfl_xor(Bs, 2);
        Bs += __shfl_xor(Bs, 4);
        float* cb = cw + (size_t)(bb0 + bl) * 32;
        cb[k] = 1.f - DTC * be * (Bm + Bs);
        cb[8 + k] = DTC * be * Bm;
        cb[16 + k] = Bm;
        if (k == 0) {
            cb[24] = Bs * (Eps[bl] + 1.f);   // sE2: stress = cuj*sE2 - sum(Bm*xi) + nup*cpj
            cb[25] = nups[bl];
        }
    }
}

// ---------------- time loop: minimal-VALU fully-unrolled body --------------
// grid 2048 x 256: one wave per batch. lane = j*8+k.
__global__ __launch_bounds__(256) void time_kernel(
    const float* __restrict__ e, const float* __restrict__ ed,
    const float* __restrict__ cw, float* __restrict__ stress,
    float* __restrict__ xi_out) {
    __shared__ float els[4][512];
    __shared__ float pls[4][512];
    const int wv = threadIdx.x >> 6;
    const int wid = (blockIdx.x << 2) + wv;
    const int lane = threadIdx.x & 63;
    const int j = lane >> 3, k = lane & 7;

    const float* eb = e + (size_t)wid * NT;
    const float* edb = ed + (size_t)wid * NT;
    gl_lds16(eb + lane * 4, &els[wv][0]);
    gl_lds16(eb + 256 + lane * 4, &els[wv][256]);
    gl_lds16(edb + lane * 4, &pls[wv][0]);
    gl_lds16(edb + 256 + lane * 4, &pls[wv][256]);

    const float* cb = cw + (size_t)wid * 32;
    const float a = cb[k];
    const float c = cb[8 + k];
    const float Bm = cb[16 + k];
    const float sE2 = cb[24];
    const float nup = cb[25];
    // staged e/ed must land before LDS reads
    asm volatile("s_waitcnt vmcnt(0)" ::: "memory");

    const float a2 = a * a, a4 = a2 * a2;
    float A = 1.f;                           // a^j
    if (j & 1) A *= a;
    if (j & 2) A *= a2;
    if (j & 4) A *= a4;
    float pw[8];                             // pw[i] = (i<j) ? a^(j-1-i)*c : 0
    {
        float run = c;
        #pragma unroll
        for (int i = 7; i >= 0; --i) {
            const bool on = (i < j);
            pw[i] = on ? run : 0.f;
            run = on ? run * a : run;
        }
    }

    float* xb = xi_out + (size_t)wid * (NT * 8);
    float* sb = stress + (size_t)wid * NT;
    const float* el = &els[wv][0];
    const float* pl = &pls[wv][0];

    float xs = 0.f;
    #pragma unroll
    for (int it = 0; it < 64; ++it) {
        const int t0 = it * 8;               // compile-time: imm LDS offsets
        const float4 q0 = *(const float4*)(el + t0);      // uniform broadcast
        const float4 q1 = *(const float4*)(el + t0 + 4);
        const float cuj = el[t0 + j];        // 8-addr grouped read
        const float cpj = pl[t0 + j];
        float xi_j = A * xs;
        xi_j = fmaf(pw[0], q0.x, xi_j);
        xi_j = fmaf(pw[1], q0.y, xi_j);
        xi_j = fmaf(pw[2], q0.z, xi_j);
        xi_j = fmaf(pw[3], q0.w, xi_j);
        xi_j = fmaf(pw[4], q1.x, xi_j);
        xi_j = fmaf(pw[5], q1.y, xi_j);
        xi_j = fmaf(pw[6], q1.z, xi_j);
        xi_j = fmaf(pw[7], q1.w, xi_j);
        xb[t0 * 8 + lane] = xi_j;            // coalesced 256B/wave
        float r = Bm * xi_j;                 // stress needs -sum_k Bm*xi
        r = dpp_add(r, 0xB1);
        r = dpp_add(r, 0x4E);
        r = dpp_add(r, 0x141);
        if (k == 0)
            sb[t0 + j] = fmaf(cuj, sE2, fmaf(nup, cpj, -r));
        // carry: x(t0+8) = a * x(t0+7) + c*u7 ; x(t0+7) in lane 56+k
        xs = fmaf(a, __shfl(xi_j, 56 + k), c * q1.w);
    }
}

extern "C" void kernel_launch(void* const* d_in, const int* in_sizes, int n_in,
                              void* d_out, int out_size, void* d_ws, size_t ws_size,
                              hipStream_t stream) {
    const float* e   = (const float*)d_in[0];
    const float* ed  = (const float*)d_in[1];
    const float* E   = (const float*)d_in[2];
    const float* nu  = (const float*)d_in[3];
    const float* Bw1 = (const float*)d_in[4];
    const float* Bb1 = (const float*)d_in[5];
    const float* Bw2 = (const float*)d_in[6];
    const float* Bb2 = (const float*)d_in[7];
    const float* bw1 = (const float*)d_in[8];
    const float* bb1 = (const float*)d_in[9];
    const float* bw2 = (const float*)d_in[10];
    const float* bb2 = (const float*)d_in[11];

    float* out = (float*)d_out;
    float* stress = out;                        // [B*T] floats
    float* xi = out + (size_t)NB * NT;          // [B*T*8] floats
    ushort* Wt = (ushort*)d_ws;                 // 256 KB tiled weights
    float* cw = (float*)((char*)d_ws + (1 << 20));   // 1 MB coefs

    wtrans_kernel<<<128, 256, 0, stream>>>(Bw1, bw1, Wt);
    enc_kernel<<<512, 1024, 0, stream>>>(E, nu, Wt, Bb1, bb1,
                                         Bw2, Bb2, bw2, bb2, cw);
    time_kernel<<<2048, 256, 0, stream>>>(e, ed, cw, stress, xi);
}